// Round 6
// baseline (137.678 us; speedup 1.0000x reference)
//
#include <hip/hip_runtime.h>
#include <math.h>

#define Q 100
#define NC 81
#define NV 117
#define MAXK 48           // staged contested rows cap (fallback beyond; ~impossible)
#define NV4 2925          // Q*NV/4 float4s per batch (16B-aligned)
#define WSB 202           // u64s per batch in ws: killset[200] + killrow[2]

// ---------------------------------------------------------------------------
// K_A: softmax/argmax + scores/labels/boxes + label-bucketed masks + (rare)
// serial greedy. Emits per-batch killset (which (row,col) of vs get -1) into
// d_ws. Does NOT touch the 96 MB vs stream. One block per batch, 512 thr.
// Numerics: argmax on raw logits (exact); IoU chain __f*_rn (bit-exact vs np,
// protects iou>0.7); softmax/sigmoid __expf/rcp (~1e-6 rel, threshold-safe).
// ---------------------------------------------------------------------------
__global__ __launch_bounds__(512) void k_prep(
    const float*  __restrict__ obj_logits,   // (B,Q,81)
    const float*  __restrict__ verb_logits,  // (B,Q,117)
    const float*  __restrict__ sub_boxes,    // (B,Q,4) cxcywh
    const float*  __restrict__ obj_boxes,    // (B,Q,4)
    const int*    __restrict__ target_sizes, // (B,2) h,w
    float* __restrict__ out_scores,          // (B,Q)
    float* __restrict__ out_labels,          // (B,2Q)
    float* __restrict__ out_boxes,           // (B,2Q,4)
    unsigned long long* __restrict__ wsk)    // (B, WSB)
{
    __shared__ float  score_s[Q];
    __shared__ int    labi[Q];
    __shared__ float4 sb4[Q], ob4[Q];
    __shared__ float  area_s[Q], area_o[Q];
    __shared__ unsigned long long lbl_bits[NC - 1][2];
    __shared__ unsigned long long mask_s[2 * Q];
    __shared__ unsigned long long killset_s[2 * Q];
    __shared__ unsigned long long krow_s[2];
    __shared__ int   clist_s[Q];
    __shared__ float col_s[Q];
    __shared__ float vsrow[MAXK * 101];
    __shared__ int   anyconf, Ksh;

    const int b    = blockIdx.x;
    const int tid  = threadIdx.x;
    const int sl   = tid & 15;
    const int r16  = tid >> 4;           // 0..31

    if (tid == 0) { anyconf = 0; krow_s[0] = 0ull; krow_s[1] = 0ull; }
    if (tid < 2 * Q) killset_s[tid] = 0ull;
    if (tid < 2 * (NC - 1)) ((unsigned long long*)lbl_bits)[tid] = 0ull;

    // ---- softmax score + argmax label, row16 layout ----
    for (int qi = r16; qi < Q; qi += 32) {
        const float* lp = obj_logits + ((size_t)b * Q + qi) * NC;
        float v[5];
        #pragma unroll
        for (int c = 0; c < 5; ++c) v[c] = lp[sl + c * 16];
        const float l80 = lp[80];

        float bv = v[0]; int bi = sl;            // raw-logit argmax, exact
        #pragma unroll
        for (int c = 1; c < 5; ++c)
            if (v[c] > bv) { bv = v[c]; bi = sl + c * 16; }
        #pragma unroll
        for (int d = 1; d < 16; d <<= 1) {
            float ov = __shfl_xor(bv, d, 16);
            int   oi = __shfl_xor(bi, d, 16);
            if (ov > bv || (ov == bv && oi < bi)) { bv = ov; bi = oi; }
        }
        const float m = fmaxf(bv, l80);

        float s = (sl == 0) ? __expf(l80 - m) : 0.f;
        #pragma unroll
        for (int c = 0; c < 5; ++c) s += __expf(v[c] - m);
        #pragma unroll
        for (int d = 1; d < 16; d <<= 1) s += __shfl_xor(s, d, 16);

        if (sl == 0) {
            score_s[qi] = __fmul_rn(__expf(bv - m), __builtin_amdgcn_rcpf(s));
            labi[qi] = bi;
        }
    }
    __syncthreads();

    // ---- boxes (bit-exact) + scores/labels writes + label buckets ----
    if (tid < 2 * Q) {
        const int q = (tid < Q) ? tid : tid - Q;
        const float fh = (float)target_sizes[2 * b];
        const float fw = (float)target_sizes[2 * b + 1];
        const float4* src = reinterpret_cast<const float4*>(tid < Q ? sub_boxes : obj_boxes);
        float4 cxy = src[(size_t)b * Q + q];
        float hw = __fmul_rn(0.5f, cxy.z);
        float hh = __fmul_rn(0.5f, cxy.w);
        float4 box;
        box.x = __fmul_rn(__fsub_rn(cxy.x, hw), fw);
        box.y = __fmul_rn(__fsub_rn(cxy.y, hh), fh);
        box.z = __fmul_rn(__fadd_rn(cxy.x, hw), fw);
        box.w = __fmul_rn(__fadd_rn(cxy.y, hh), fh);
        float area = __fmul_rn(__fsub_rn(box.z, box.x), __fsub_rn(box.w, box.y));
        if (tid < Q) { sb4[q] = box; area_s[q] = area; }
        else         { ob4[q] = box; area_o[q] = area; }
        reinterpret_cast<float4*>(out_boxes)[(size_t)b * 2 * Q + tid] = box;
        out_labels[(size_t)b * 2 * Q + tid] = (tid < Q) ? 0.0f : (float)labi[q];
    }
    if (tid < Q) {
        out_scores[(size_t)b * Q + tid] = score_s[tid];
        atomicOr(&lbl_bits[labi[tid]][tid >> 6], 1ull << (tid & 63));
    }
    __syncthreads();

    // ---- masks: only same-label candidates ----
    if (tid < Q) {
        const int j = tid;
        const float4 sj = sb4[j]; const float asj = area_s[j];
        const float4 oj = ob4[j]; const float aoj = area_o[j];
        const int lj = labi[j];
        unsigned long long bits[2] = {0ull, 0ull};
        #pragma unroll
        for (int w = 0; w < 2; ++w) {
            unsigned long long mm = lbl_bits[lj][w];
            if (w == (j >> 6)) mm &= ~(1ull << (j & 63));
            while (mm) {
                int kb = __builtin_ctzll(mm); mm &= mm - 1;
                int k = kb + w * 64;
                float4 sk = sb4[k];
                float wx = fmaxf(__fsub_rn(fminf(sj.z, sk.z), fmaxf(sj.x, sk.x)), 0.f);
                float wy = fmaxf(__fsub_rn(fminf(sj.w, sk.w), fmaxf(sj.y, sk.y)), 0.f);
                float inter = __fmul_rn(wx, wy);
                float uni = __fsub_rn(__fadd_rn(asj, area_s[k]), inter);
                float ious = __fdiv_rn(inter, uni);
                float4 ok = ob4[k];
                wx = fmaxf(__fsub_rn(fminf(oj.z, ok.z), fmaxf(oj.x, ok.x)), 0.f);
                wy = fmaxf(__fsub_rn(fminf(oj.w, ok.w), fmaxf(oj.y, ok.y)), 0.f);
                inter = __fmul_rn(wx, wy);
                uni = __fsub_rn(__fadd_rn(aoj, area_o[k]), inter);
                float iouo = __fdiv_rn(inter, uni);
                if (ious != ious || iouo != iouo) continue;  // np.minimum NaN
                if (fminf(ious, iouo) > 0.7f) bits[w] |= 1ull << kb;
            }
        }
        mask_s[2 * j]     = bits[0];
        mask_s[2 * j + 1] = bits[1];
        if (bits[0] | bits[1]) anyconf = 1;
    }
    __syncthreads();

    if (anyconf) {
        // contested list
        if (tid == 0) {
            int K = 0;
            for (int q = 0; q < Q; ++q)
                if (mask_s[2 * q] | mask_s[2 * q + 1]) clist_s[K++] = q;
            Ksh = K;
        }
        __syncthreads();
        const int K = Ksh;
        const bool staged = (K <= MAXK);

        // stage contested vs values computed from verb_logits (cols 0..99)
        // NOTE: identical formula to k_stream -> consistent ordering.
        if (staged) {
            for (int idx = tid; idx < K * Q; idx += 512) {
                int k = idx / Q, i = idx - k * Q;
                int c = clist_s[k];
                float x = verb_logits[(size_t)b * Q * NV + c * NV + i];
                float sg = __builtin_amdgcn_rcpf(__fadd_rn(1.0f, __expf(-x)));
                vsrow[k * 101 + i] = __fmul_rn(sg, score_s[c]);
            }
        }
        __syncthreads();

        // serial greedy over 100 class-steps (steps >= 100 are OOB no-ops;
        // vs[c][i] decremented at step c iff query i suppressed at step c)
        if (tid == 0) {
            for (int i = 0; i < Q; ++i) {
                for (int k = 0; k < K; ++k) {
                    int c = clist_s[k];
                    float v;
                    if (staged) v = vsrow[k * 101 + i];
                    else {
                        float x = verb_logits[(size_t)b * Q * NV + c * NV + i];
                        float sg = __builtin_amdgcn_rcpf(__fadd_rn(1.0f, __expf(-x)));
                        v = __fmul_rn(sg, score_s[c]);
                    }
                    if ((killset_s[2 * c + (i >> 6)] >> (i & 63)) & 1ull)
                        v = __fsub_rn(v, 1.0f);
                    col_s[k] = v;
                }
                unsigned long long alive0 = ~0ull, alive1 = (1ull << 36) - 1;
                unsigned long long supp0 = 0ull, supp1 = 0ull;
                for (int t = 0; t < K; ++t) {   // stable desc = argsort(-col)
                    float best = col_s[0]; int bk = 0;
                    for (int k = 1; k < K; ++k) { float ck = col_s[k]; if (ck > best) { best = ck; bk = k; } }
                    col_s[bk] = -3.0e38f;
                    int q = clist_s[bk];
                    bool al = (q < 64) ? ((alive0 >> q) & 1ull) : ((alive1 >> (q - 64)) & 1ull);
                    if (al) {
                        unsigned long long m0 = mask_s[2 * q], m1 = mask_s[2 * q + 1];
                        supp0 |= alive0 & m0;
                        supp1 |= alive1 & m1;
                        alive0 &= ~m0;
                        alive1 &= ~m1;
                        if (q < 64) alive0 &= ~(1ull << q); else alive1 &= ~(1ull << (q - 64));
                    }
                }
                killset_s[2 * i]     = supp0;
                killset_s[2 * i + 1] = supp1;
            }
            unsigned long long kr0 = 0ull, kr1 = 0ull;
            for (int i = 0; i < Q; ++i)
                if (killset_s[2 * i] | killset_s[2 * i + 1]) {
                    if (i < 64) kr0 |= 1ull << i; else kr1 |= 1ull << (i - 64);
                }
            krow_s[0] = kr0; krow_s[1] = kr1;
        }
        __syncthreads();
    }

    // ---- emit killset + killrow (ws is poisoned -> always write) ----
    if (tid < WSB)
        wsk[(size_t)b * WSB + tid] = (tid < 2 * Q) ? killset_s[tid] : krow_s[tid - 2 * Q];
}

// ---------------------------------------------------------------------------
// K_B: pure vs stream: sigmoid(verb)*score with inline -1 deltas.
// One block per batch, 512 thr, ~2 KB LDS -> full occupancy (32 waves/CU).
// Common path per float4: 1 magic-div pair + 1 LDS score read + killrow reg
// test. Kill path touched only for batches/rows flagged in killrow.
// ---------------------------------------------------------------------------
__global__ __launch_bounds__(512) void k_stream(
    const float4* __restrict__ verb4,        // (B, 2925)
    const float*  __restrict__ scores,       // (B,Q)
    const unsigned long long* __restrict__ wsk,
    float4* __restrict__ out4)               // (B, 2925)
{
    __shared__ float score_l[Q];
    __shared__ unsigned long long killset_l[2 * Q];

    const int b   = blockIdx.x;
    const int tid = threadIdx.x;

    if (tid < Q) score_l[tid] = scores[(size_t)b * Q + tid];
    const unsigned long long kr0 = wsk[(size_t)b * WSB + 200];  // same-addr: broadcast
    const unsigned long long kr1 = wsk[(size_t)b * WSB + 201];
    const bool anykill = (kr0 | kr1) != 0ull;
    if (anykill && tid < 2 * Q)
        killset_l[tid] = wsk[(size_t)b * WSB + tid];
    __syncthreads();

    const size_t base4 = (size_t)b * NV4;
    for (int r = tid; r < NV4; r += 512) {
        float4 x = verb4[base4 + r];
        const int e  = r * 4;
        const int q0 = (unsigned)e / 117u;
        const int q3 = (unsigned)(e + 3) / 117u;
        float o[4];
        float xv[4] = {x.x, x.y, x.z, x.w};
        if (q0 == q3) {
            const float sc = score_l[q0];
            #pragma unroll
            for (int j = 0; j < 4; ++j) {
                float sg = __builtin_amdgcn_rcpf(__fadd_rn(1.0f, __expf(-xv[j])));
                o[j] = __fmul_rn(sg, sc);
            }
            if (anykill && ((q0 < 64 ? (kr0 >> q0) : (kr1 >> (q0 - 64))) & 1ull)) {
                const int v0 = e - q0 * 117;
                #pragma unroll
                for (int j = 0; j < 4; ++j) {
                    int v = v0 + j;   // bits >= 100 never set -> safe for v<=116
                    if ((killset_l[2 * q0 + (v >> 6)] >> (v & 63)) & 1ull)
                        o[j] = __fsub_rn(o[j], 1.0f);
                }
            }
        } else {
            #pragma unroll
            for (int j = 0; j < 4; ++j) {
                int ej = e + j;
                int qj = (unsigned)ej / 117u;
                int vj = ej - qj * 117;
                float sg = __builtin_amdgcn_rcpf(__fadd_rn(1.0f, __expf(-xv[j])));
                o[j] = __fmul_rn(sg, score_l[qj]);
                if (anykill && ((qj < 64 ? (kr0 >> qj) : (kr1 >> (qj - 64))) & 1ull))
                    if ((killset_l[2 * qj + (vj >> 6)] >> (vj & 63)) & 1ull)
                        o[j] = __fsub_rn(o[j], 1.0f);
            }
        }
        out4[base4 + r] = make_float4(o[0], o[1], o[2], o[3]);
    }
}

extern "C" void kernel_launch(void* const* d_in, const int* in_sizes, int n_in,
                              void* d_out, int out_size, void* d_ws, size_t ws_size,
                              hipStream_t stream) {
    const float* obj_logits   = (const float*)d_in[0];
    const float* verb_logits  = (const float*)d_in[1];
    const float* sub_boxes    = (const float*)d_in[2];
    const float* obj_boxes    = (const float*)d_in[3];
    const int*   target_sizes = (const int*)d_in[4];
    const int B  = in_sizes[0] / (Q * NC);   // 1024

    float* out_vs     = (float*)d_out;                        // B*Q*117
    float* out_scores = out_vs + (size_t)B * Q * NV;          // B*Q
    float* out_labels = out_scores + (size_t)B * Q;           // B*2Q
    float* out_boxes  = out_labels + (size_t)B * 2 * Q;       // B*2Q*4
    unsigned long long* wsk = (unsigned long long*)d_ws;      // B*WSB u64

    k_prep<<<dim3(B), dim3(512), 0, stream>>>(
        obj_logits, verb_logits, sub_boxes, obj_boxes, target_sizes,
        out_scores, out_labels, out_boxes, wsk);

    k_stream<<<dim3(B), dim3(512), 0, stream>>>(
        (const float4*)verb_logits, out_scores, wsk, (float4*)out_vs);
}

// Round 7
// 134.246 us; speedup vs baseline: 1.0256x; 1.0256x over previous
//
#include <hip/hip_runtime.h>
#include <math.h>

#define Q 100
#define NC 81
#define NV 117
#define MAXK 48           // staged contested rows cap (fallback beyond; ~impossible)
#define NV4 2925          // Q*NV/4 float4s per batch (16B-aligned)

// ---------------------------------------------------------------------------
// Monolithic, one block per batch, 512 threads. Phase order puts the 96 MB
// verb stream LAST with no trailing barrier: all __syncthreads happen before
// the heavy traffic, so no vmcnt(0) drain stalls the stream and each wave
// retires independently (R5 had the stream sandwiched between barriers).
//  1 softmax/argmax (row16: 16 lanes/query, 3 shuffle-stages)      sync1
//  2 boxes (bit-exact) + label buckets + scores/labels writes      sync2
//  3 label-bucketed conflict masks -> anyconf                      sync3
//  4 [rare] greedy PNMS on vs values recomputed from verb_logits   sync4
//  5 vs stream: sigmoid(verb)*score with inline -1 kill application, exit
// Numerics: argmax on raw logits (exact); IoU chain __f*_rn (bit-exact vs np,
// protects iou>0.7); softmax/sigmoid __expf/rcp (~1e-6 rel, threshold-safe;
// phase-4 staging uses the IDENTICAL formula as phase 5 -> consistent order).
// ---------------------------------------------------------------------------
__global__ __launch_bounds__(512) void hoi_fused(
    const float*  __restrict__ obj_logits,   // (B,Q,81)
    const float*  __restrict__ verb_logits,  // (B,Q,117)
    const float*  __restrict__ sub_boxes,    // (B,Q,4) cxcywh
    const float*  __restrict__ obj_boxes,    // (B,Q,4)
    const int*    __restrict__ target_sizes, // (B,2) h,w
    float* __restrict__ out_vs,              // (B,Q,117)
    float* __restrict__ out_scores,          // (B,Q)
    float* __restrict__ out_labels,          // (B,2Q)
    float* __restrict__ out_boxes)           // (B,2Q,4)
{
    __shared__ float  score_s[Q];
    __shared__ int    labi[Q];
    __shared__ float4 sb4[Q], ob4[Q];
    __shared__ float  area_s[Q], area_o[Q];
    __shared__ unsigned long long lbl_bits[NC - 1][2];
    __shared__ unsigned long long mask_s[2 * Q];
    __shared__ unsigned long long killset_s[2 * Q];
    __shared__ int   clist_s[Q];
    __shared__ float col_s[Q];
    __shared__ float vsrow[MAXK * 101];
    __shared__ int   anyconf, Ksh;

    const int b    = blockIdx.x;
    const int tid  = threadIdx.x;
    const int sl   = tid & 15;
    const int r16  = tid >> 4;           // 0..31

    if (tid == 0) anyconf = 0;
    if (tid < 2 * Q) killset_s[tid] = 0ull;
    if (tid < 2 * (NC - 1)) ((unsigned long long*)lbl_bits)[tid] = 0ull;

    // ---- Phase 1: softmax score + argmax label (row16 layout) ----
    for (int qi = r16; qi < Q; qi += 32) {
        const float* lp = obj_logits + ((size_t)b * Q + qi) * NC;
        float v[5];
        #pragma unroll
        for (int c = 0; c < 5; ++c) v[c] = lp[sl + c * 16];
        const float l80 = lp[80];

        float bv = v[0]; int bi = sl;            // raw-logit argmax, exact
        #pragma unroll
        for (int c = 1; c < 5; ++c)
            if (v[c] > bv) { bv = v[c]; bi = sl + c * 16; }
        #pragma unroll
        for (int d = 1; d < 16; d <<= 1) {
            float ov = __shfl_xor(bv, d, 16);
            int   oi = __shfl_xor(bi, d, 16);
            if (ov > bv || (ov == bv && oi < bi)) { bv = ov; bi = oi; }
        }
        const float m = fmaxf(bv, l80);

        float s = (sl == 0) ? __expf(l80 - m) : 0.f;
        #pragma unroll
        for (int c = 0; c < 5; ++c) s += __expf(v[c] - m);
        #pragma unroll
        for (int d = 1; d < 16; d <<= 1) s += __shfl_xor(s, d, 16);

        if (sl == 0) {
            score_s[qi] = __fmul_rn(__expf(bv - m), __builtin_amdgcn_rcpf(s));
            labi[qi] = bi;
        }
    }
    __syncthreads();   // sync1

    // ---- Phase 2: boxes (bit-exact) + scores/labels + label buckets ----
    if (tid < 2 * Q) {
        const int q = (tid < Q) ? tid : tid - Q;
        const float fh = (float)target_sizes[2 * b];
        const float fw = (float)target_sizes[2 * b + 1];
        const float4* src = reinterpret_cast<const float4*>(tid < Q ? sub_boxes : obj_boxes);
        float4 cxy = src[(size_t)b * Q + q];
        float hw = __fmul_rn(0.5f, cxy.z);
        float hh = __fmul_rn(0.5f, cxy.w);
        float4 box;
        box.x = __fmul_rn(__fsub_rn(cxy.x, hw), fw);
        box.y = __fmul_rn(__fsub_rn(cxy.y, hh), fh);
        box.z = __fmul_rn(__fadd_rn(cxy.x, hw), fw);
        box.w = __fmul_rn(__fadd_rn(cxy.y, hh), fh);
        float area = __fmul_rn(__fsub_rn(box.z, box.x), __fsub_rn(box.w, box.y));
        if (tid < Q) { sb4[q] = box; area_s[q] = area; }
        else         { ob4[q] = box; area_o[q] = area; }
        reinterpret_cast<float4*>(out_boxes)[(size_t)b * 2 * Q + tid] = box;
        out_labels[(size_t)b * 2 * Q + tid] = (tid < Q) ? 0.0f : (float)labi[q];
    }
    if (tid < Q) {
        out_scores[(size_t)b * Q + tid] = score_s[tid];
        atomicOr(&lbl_bits[labi[tid]][tid >> 6], 1ull << (tid & 63));
    }
    __syncthreads();   // sync2

    // ---- Phase 3: conflict masks (same-label candidates only) ----
    if (tid < Q) {
        const int j = tid;
        const float4 sj = sb4[j]; const float asj = area_s[j];
        const float4 oj = ob4[j]; const float aoj = area_o[j];
        const int lj = labi[j];
        unsigned long long bits[2] = {0ull, 0ull};
        #pragma unroll
        for (int w = 0; w < 2; ++w) {
            unsigned long long mm = lbl_bits[lj][w];
            if (w == (j >> 6)) mm &= ~(1ull << (j & 63));
            while (mm) {
                int kb = __builtin_ctzll(mm); mm &= mm - 1;
                int k = kb + w * 64;
                float4 sk = sb4[k];
                float wx = fmaxf(__fsub_rn(fminf(sj.z, sk.z), fmaxf(sj.x, sk.x)), 0.f);
                float wy = fmaxf(__fsub_rn(fminf(sj.w, sk.w), fmaxf(sj.y, sk.y)), 0.f);
                float inter = __fmul_rn(wx, wy);
                float uni = __fsub_rn(__fadd_rn(asj, area_s[k]), inter);
                float ious = __fdiv_rn(inter, uni);
                float4 ok = ob4[k];
                wx = fmaxf(__fsub_rn(fminf(oj.z, ok.z), fmaxf(oj.x, ok.x)), 0.f);
                wy = fmaxf(__fsub_rn(fminf(oj.w, ok.w), fmaxf(oj.y, ok.y)), 0.f);
                inter = __fmul_rn(wx, wy);
                uni = __fsub_rn(__fadd_rn(aoj, area_o[k]), inter);
                float iouo = __fdiv_rn(inter, uni);
                if (ious != ious || iouo != iouo) continue;  // np.minimum NaN
                if (fminf(ious, iouo) > 0.7f) bits[w] |= 1ull << kb;
            }
        }
        mask_s[2 * j]     = bits[0];
        mask_s[2 * j + 1] = bits[1];
        if (bits[0] | bits[1]) anyconf = 1;   // benign race, same value
    }
    __syncthreads();   // sync3: masks + anyconf ready

    // ---- Phase 4 (rare): greedy PNMS -> killset ----
    if (anyconf) {
        if (tid == 0) {
            int K = 0;
            for (int q = 0; q < Q; ++q)
                if (mask_s[2 * q] | mask_s[2 * q + 1]) clist_s[K++] = q;
            Ksh = K;
        }
        __syncthreads();
        const int K = Ksh;
        const bool staged = (K <= MAXK);

        // stage contested vs values from verb_logits (cols 0..99 only matter;
        // IDENTICAL formula to phase 5 -> consistent ordering)
        if (staged) {
            for (int idx = tid; idx < K * Q; idx += 512) {
                int k = idx / Q, i = idx - k * Q;
                int c = clist_s[k];
                float x = verb_logits[(size_t)b * Q * NV + c * NV + i];
                float sg = __builtin_amdgcn_rcpf(__fadd_rn(1.0f, __expf(-x)));
                vsrow[k * 101 + i] = __fmul_rn(sg, score_s[c]);
            }
        }
        __syncthreads();

        // serial greedy over 100 class-steps (steps >= 100 are OOB no-ops;
        // vs[c][i] decremented at step c iff query i suppressed at step c,
        // killset_s[c] bit i — steps >= i still zero at step i)
        if (tid == 0) {
            for (int i = 0; i < Q; ++i) {
                for (int k = 0; k < K; ++k) {
                    int c = clist_s[k];
                    float v;
                    if (staged) v = vsrow[k * 101 + i];
                    else {
                        float x = verb_logits[(size_t)b * Q * NV + c * NV + i];
                        float sg = __builtin_amdgcn_rcpf(__fadd_rn(1.0f, __expf(-x)));
                        v = __fmul_rn(sg, score_s[c]);
                    }
                    if ((killset_s[2 * c + (i >> 6)] >> (i & 63)) & 1ull)
                        v = __fsub_rn(v, 1.0f);
                    col_s[k] = v;
                }
                unsigned long long alive0 = ~0ull, alive1 = (1ull << 36) - 1;
                unsigned long long supp0 = 0ull, supp1 = 0ull;
                for (int t = 0; t < K; ++t) {   // stable desc = argsort(-col)
                    float best = col_s[0]; int bk = 0;
                    for (int k = 1; k < K; ++k) { float ck = col_s[k]; if (ck > best) { best = ck; bk = k; } }
                    col_s[bk] = -3.0e38f;
                    int q = clist_s[bk];
                    bool al = (q < 64) ? ((alive0 >> q) & 1ull) : ((alive1 >> (q - 64)) & 1ull);
                    if (al) {
                        unsigned long long m0 = mask_s[2 * q], m1 = mask_s[2 * q + 1];
                        supp0 |= alive0 & m0;
                        supp1 |= alive1 & m1;
                        alive0 &= ~m0;
                        alive1 &= ~m1;
                        if (q < 64) alive0 &= ~(1ull << q); else alive1 &= ~(1ull << (q - 64));
                    }
                }
                killset_s[2 * i]     = supp0;
                killset_s[2 * i + 1] = supp1;
            }
        }
        __syncthreads();   // sync4 (rare path only)
    }

    // ---- Phase 5: terminal vs stream, no trailing barrier ----
    // vs[q][v] = sigmoid(verb)*score - (killset_s[q] bit v ? 1 : 0)
    // (killset bits >= 100 never set -> safe for v in 100..116)
    {
        const size_t base4 = (size_t)b * NV4;
        const float4* v4 = reinterpret_cast<const float4*>(verb_logits);
        float4* ovs4 = reinterpret_cast<float4*>(out_vs);
        const bool kills = anyconf;   // block-uniform
        for (int r = tid; r < NV4; r += 512) {
            float4 x = v4[base4 + r];
            const int e = r * 4;
            float xv[4] = {x.x, x.y, x.z, x.w};
            float o[4];
            #pragma unroll
            for (int j = 0; j < 4; ++j) {
                int ej = e + j;
                int qj = (unsigned)ej / 117u;           // magic-mul
                float sg = __builtin_amdgcn_rcpf(__fadd_rn(1.0f, __expf(-xv[j])));
                o[j] = __fmul_rn(sg, score_s[qj]);
                if (kills) {
                    int vj = ej - qj * 117;
                    if ((killset_s[2 * qj + (vj >> 6)] >> (vj & 63)) & 1ull)
                        o[j] = __fsub_rn(o[j], 1.0f);
                }
            }
            ovs4[base4 + r] = make_float4(o[0], o[1], o[2], o[3]);
        }
    }
}

extern "C" void kernel_launch(void* const* d_in, const int* in_sizes, int n_in,
                              void* d_out, int out_size, void* d_ws, size_t ws_size,
                              hipStream_t stream) {
    const float* obj_logits   = (const float*)d_in[0];
    const float* verb_logits  = (const float*)d_in[1];
    const float* sub_boxes    = (const float*)d_in[2];
    const float* obj_boxes    = (const float*)d_in[3];
    const int*   target_sizes = (const int*)d_in[4];
    const int B  = in_sizes[0] / (Q * NC);   // 1024

    float* out_vs     = (float*)d_out;                        // B*Q*117
    float* out_scores = out_vs + (size_t)B * Q * NV;          // B*Q
    float* out_labels = out_scores + (size_t)B * Q;           // B*2Q
    float* out_boxes  = out_labels + (size_t)B * 2 * Q;       // B*2Q*4

    hoi_fused<<<dim3(B), dim3(512), 0, stream>>>(
        obj_logits, verb_logits, sub_boxes, obj_boxes, target_sizes,
        out_vs, out_scores, out_labels, out_boxes);
}

// Round 8
// 130.595 us; speedup vs baseline: 1.0542x; 1.0280x over previous
//
#include <hip/hip_runtime.h>
#include <math.h>

#define Q 100
#define NC 81
#define NV 117
#define MAXK 48           // staged contested rows cap (fallback beyond; ~impossible)
#define NV4 2925          // Q*NV/4 float4s per batch (16B-aligned: 100*117*4B = 2925*16B)

// ---------------------------------------------------------------------------
// Monolithic: one block per batch, 512 threads (8 waves). R5 structure —
// measured best (131.4 µs): the 96 MB verb stream is issued in region 2, so
// its in-flight stores overlap the mask-phase VALU work (R7's stream-last
// variant lost that overlap and regressed).
//  A: softmax/argmax, row16 layout (16 lanes/query, 3 shuffle-stages/query)
//  R2: boxes (bit-exact) + label buckets + verb-sigmoid streaming (float4)
//  masks (label-bucketed, ~1.25 candidates/query) -> fast-path exit
//  rare slow path: thread-0 serial greedy (reference semantics: row-i scatter
//  quirk, OOB-drop for class-steps >= 100), parallel RMW fixup.
// Numerics: argmax on raw logits (exact); IoU chain __f*_rn (bit-exact vs np,
// protects the 0.7 threshold); softmax/sigmoid use __expf/rcp (~1e-6 rel,
// only affects threshold-checked float outputs).
// ---------------------------------------------------------------------------
__global__ __launch_bounds__(512) void hoi_fused(
    const float*  __restrict__ obj_logits,   // (B,Q,81)
    const float4* __restrict__ verb4,        // (B, 2925)
    const float*  __restrict__ sub_boxes,    // (B,Q,4) cxcywh
    const float*  __restrict__ obj_boxes,    // (B,Q,4)
    const int*    __restrict__ target_sizes, // (B,2) h,w
    float* __restrict__ out_vs,              // (B,Q,117)
    float* __restrict__ out_scores,          // (B,Q)
    float* __restrict__ out_labels,          // (B,2Q)
    float* __restrict__ out_boxes)           // (B,2Q,4)
{
    __shared__ float  score_s[Q];
    __shared__ int    labi[Q];
    __shared__ float4 sb4[Q], ob4[Q];
    __shared__ float  area_s[Q], area_o[Q];
    __shared__ unsigned long long lbl_bits[NC - 1][2];  // per-label query bitset
    __shared__ unsigned long long mask_s[2 * Q];        // conflict mask per query
    __shared__ unsigned long long killset_s[2 * Q];     // per step i: killed-at-i
    __shared__ int   clist_s[Q];
    __shared__ float col_s[Q];
    __shared__ float vsrow[MAXK * 101];
    __shared__ int   anyconf, Ksh;

    const int b    = blockIdx.x;
    const int tid  = threadIdx.x;
    const int lane = tid & 63;
    const int sl   = lane & 15;
    const int r16  = tid >> 4;           // 0..31 row16 id

    // ---- init (pre-sync1) ----
    if (tid == 0) anyconf = 0;
    if (tid < 2 * Q) killset_s[tid] = 0ull;
    if (tid < 2 * (NC - 1)) ((unsigned long long*)lbl_bits)[tid] = 0ull;

    // ---- Phase A: softmax score + argmax label, row16 layout ----
    for (int qi = r16; qi < Q; qi += 32) {
        const float* lp = obj_logits + ((size_t)b * Q + qi) * NC;
        float v[5];
        #pragma unroll
        for (int c = 0; c < 5; ++c) v[c] = lp[sl + c * 16];
        const float l80 = lp[80];

        // argmax over classes 0..79 on RAW logits (exact, first-max-wins)
        float bv = v[0]; int bi = sl;
        #pragma unroll
        for (int c = 1; c < 5; ++c)
            if (v[c] > bv) { bv = v[c]; bi = sl + c * 16; }
        #pragma unroll
        for (int d = 1; d < 16; d <<= 1) {
            float ov = __shfl_xor(bv, d, 16);
            int   oi = __shfl_xor(bi, d, 16);
            if (ov > bv || (ov == bv && oi < bi)) { bv = ov; bi = oi; }
        }
        const float m = fmaxf(bv, l80);       // stabilizer over all 81

        float s = (sl == 0) ? __expf(l80 - m) : 0.f;
        #pragma unroll
        for (int c = 0; c < 5; ++c) s += __expf(v[c] - m);
        #pragma unroll
        for (int d = 1; d < 16; d <<= 1) s += __shfl_xor(s, d, 16);

        if (sl == 0) {
            score_s[qi] = __fmul_rn(__expf(bv - m), __builtin_amdgcn_rcpf(s));
            labi[qi] = bi;
        }
    }
    __syncthreads();   // sync1: score_s, labi ready

    // ---- Region 2a: boxes (bit-exact) + coalesced scores/labels writes ----
    if (tid < 2 * Q) {
        const int q = (tid < Q) ? tid : tid - Q;
        const float fh = (float)target_sizes[2 * b];
        const float fw = (float)target_sizes[2 * b + 1];
        const float4* src = reinterpret_cast<const float4*>(tid < Q ? sub_boxes : obj_boxes);
        float4 cxy = src[(size_t)b * Q + q];
        float hw = __fmul_rn(0.5f, cxy.z);
        float hh = __fmul_rn(0.5f, cxy.w);
        float4 box;
        box.x = __fmul_rn(__fsub_rn(cxy.x, hw), fw);
        box.y = __fmul_rn(__fsub_rn(cxy.y, hh), fh);
        box.z = __fmul_rn(__fadd_rn(cxy.x, hw), fw);
        box.w = __fmul_rn(__fadd_rn(cxy.y, hh), fh);
        float area = __fmul_rn(__fsub_rn(box.z, box.x), __fsub_rn(box.w, box.y));
        if (tid < Q) { sb4[q] = box; area_s[q] = area; }
        else         { ob4[q] = box; area_o[q] = area; }
        reinterpret_cast<float4*>(out_boxes)[(size_t)b * 2 * Q + tid] = box;
        out_labels[(size_t)b * 2 * Q + tid] = (tid < Q) ? 0.0f : (float)labi[q];
    }
    if (tid < Q) {
        out_scores[(size_t)b * Q + tid] = score_s[tid];
        atomicOr(&lbl_bits[labi[tid]][tid >> 6], 1ull << (tid & 63));  // buckets
    }

    // ---- Region 2b: verb sigmoid streaming (all 512 threads) ----
    {
        const size_t base4 = (size_t)b * NV4;
        float4* ovs4 = reinterpret_cast<float4*>(out_vs);
        for (int idx = tid; idx < NV4; idx += 512) {
            float4 x = verb4[base4 + idx];
            float xv[4] = {x.x, x.y, x.z, x.w};
            float r[4];
            #pragma unroll
            for (int j = 0; j < 4; ++j) {
                int lq = (idx * 4 + j) / NV;          // magic-mul, local query
                float sg = __builtin_amdgcn_rcpf(__fadd_rn(1.0f, __expf(-xv[j])));
                r[j] = __fmul_rn(sg, score_s[lq]);
            }
            ovs4[base4 + idx] = make_float4(r[0], r[1], r[2], r[3]);
        }
    }
    __syncthreads();   // sync2: sb4/ob4/areas/lbl_bits ready

    // ---- masks: only same-label candidates ----
    if (tid < Q) {
        const int j = tid;
        const float4 sj = sb4[j]; const float asj = area_s[j];
        const float4 oj = ob4[j]; const float aoj = area_o[j];
        const int lj = labi[j];
        unsigned long long bits[2] = {0ull, 0ull};
        #pragma unroll
        for (int w = 0; w < 2; ++w) {
            unsigned long long mm = lbl_bits[lj][w];
            if (w == (j >> 6)) mm &= ~(1ull << (j & 63));   // exclude self
            while (mm) {
                int kb = __builtin_ctzll(mm); mm &= mm - 1;
                int k = kb + w * 64;
                float4 sk = sb4[k];
                float wx = fmaxf(__fsub_rn(fminf(sj.z, sk.z), fmaxf(sj.x, sk.x)), 0.f);
                float wy = fmaxf(__fsub_rn(fminf(sj.w, sk.w), fmaxf(sj.y, sk.y)), 0.f);
                float inter = __fmul_rn(wx, wy);
                float uni = __fsub_rn(__fadd_rn(asj, area_s[k]), inter);
                float ious = __fdiv_rn(inter, uni);
                float4 ok = ob4[k];
                wx = fmaxf(__fsub_rn(fminf(oj.z, ok.z), fmaxf(oj.x, ok.x)), 0.f);
                wy = fmaxf(__fsub_rn(fminf(oj.w, ok.w), fmaxf(oj.y, ok.y)), 0.f);
                inter = __fmul_rn(wx, wy);
                uni = __fsub_rn(__fadd_rn(aoj, area_o[k]), inter);
                float iouo = __fdiv_rn(inter, uni);
                if (ious != ious || iouo != iouo) continue;  // np.minimum NaN -> false
                if (fminf(ious, iouo) > 0.7f) bits[w] |= 1ull << kb;
            }
        }
        mask_s[2 * j]     = bits[0];
        mask_s[2 * j + 1] = bits[1];
        if (bits[0] | bits[1]) anyconf = 1;   // benign race, same value
    }
    __syncthreads();   // sync3: masks + anyconf ready; streaming writes drained

    if (!anyconf) return;            // fast path (common case)

    // ---- slow path: contested list ----
    if (tid == 0) {
        int K = 0;
        for (int q = 0; q < Q; ++q)
            if (mask_s[2 * q] | mask_s[2 * q + 1]) clist_s[K++] = q;
        Ksh = K;
    }
    __syncthreads();
    const int K = Ksh;
    const bool staged = (K <= MAXK);

    // stage contested vs rows (cols 0..99 only matter); L2-hot re-read
    if (staged) {
        for (int idx = tid; idx < K * Q; idx += 512) {
            int k = idx / Q, i = idx - k * Q;
            vsrow[k * 101 + i] = out_vs[(size_t)b * Q * NV + clist_s[k] * NV + i];
        }
    }
    __syncthreads();

    // serial greedy over 100 class-steps (steps >= 100 are OOB no-ops)
    if (tid == 0) {
        for (int i = 0; i < Q; ++i) {
            // vs[c][i] was decremented at class-step c iff query i suppressed
            // at step c (killset_s[c] bit i; steps >= i still zero).
            for (int k = 0; k < K; ++k) {
                int c = clist_s[k];
                float v = staged ? vsrow[k * 101 + i]
                                 : out_vs[(size_t)b * Q * NV + c * NV + i];
                if ((killset_s[2 * c + (i >> 6)] >> (i & 63)) & 1ull)
                    v = __fsub_rn(v, 1.0f);
                col_s[k] = v;
            }
            unsigned long long alive0 = ~0ull, alive1 = (1ull << 36) - 1;
            unsigned long long supp0 = 0ull, supp1 = 0ull;
            // stable descending selection == argsort(-col), ties -> lower index
            for (int t = 0; t < K; ++t) {
                float best = col_s[0]; int bk = 0;
                for (int k = 1; k < K; ++k) { float ck = col_s[k]; if (ck > best) { best = ck; bk = k; } }
                col_s[bk] = -3.0e38f;
                int q = clist_s[bk];
                bool al = (q < 64) ? ((alive0 >> q) & 1ull) : ((alive1 >> (q - 64)) & 1ull);
                if (al) {
                    unsigned long long m0 = mask_s[2 * q], m1 = mask_s[2 * q + 1];
                    supp0 |= alive0 & m0;
                    supp1 |= alive1 & m1;
                    alive0 &= ~m0;
                    alive1 &= ~m1;
                    if (q < 64) alive0 &= ~(1ull << q); else alive1 &= ~(1ull << (q - 64));
                }
            }
            killset_s[2 * i]     = supp0;
            killset_s[2 * i + 1] = supp1;
        }
    }
    __syncthreads();

    // apply deltas: vs[i][v] -= 1 iff query v killed at step i
    for (int idx = tid; idx < Q * Q; idx += 512) {
        int qrow = idx / Q, v = idx - qrow * Q;
        if ((killset_s[2 * qrow + (v >> 6)] >> (v & 63)) & 1ull) {
            size_t a = (size_t)b * Q * NV + qrow * NV + v;
            out_vs[a] = __fsub_rn(out_vs[a], 1.0f);
        }
    }
}

extern "C" void kernel_launch(void* const* d_in, const int* in_sizes, int n_in,
                              void* d_out, int out_size, void* d_ws, size_t ws_size,
                              hipStream_t stream) {
    const float* obj_logits   = (const float*)d_in[0];
    const float* verb_logits  = (const float*)d_in[1];
    const float* sub_boxes    = (const float*)d_in[2];
    const float* obj_boxes    = (const float*)d_in[3];
    const int*   target_sizes = (const int*)d_in[4];
    const int B  = in_sizes[0] / (Q * NC);   // 1024

    float* out_vs     = (float*)d_out;                        // B*Q*117
    float* out_scores = out_vs + (size_t)B * Q * NV;          // B*Q
    float* out_labels = out_scores + (size_t)B * Q;           // B*2Q
    float* out_boxes  = out_labels + (size_t)B * 2 * Q;       // B*2Q*4

    hoi_fused<<<dim3(B), dim3(512), 0, stream>>>(
        obj_logits, (const float4*)verb_logits,
        sub_boxes, obj_boxes, target_sizes,
        out_vs, out_scores, out_labels, out_boxes);
}